// Round 3
// baseline (939.753 us; speedup 1.0000x reference)
//
#include <hip/hip_runtime.h>
#include <hip/hip_bf16.h>

typedef _Float16 f16x8 __attribute__((ext_vector_type(8)));
typedef float    f32x4 __attribute__((ext_vector_type(4)));

#define T_STEPS 1024
#define BATCH   128
#define DH      256

// ---------------------------------------------------------------------------
// Kernel 1 (unchanged): xp = x @ W_ih^T + b_ih + b_hh -> d_out.
// f16 hi/lo split (3 MFMA passes) => ~fp32 accuracy.
// ---------------------------------------------------------------------------
#define BM 128
#define BN 128
#define BK 64

__device__ __forceinline__ void stage_tile(const float* __restrict__ src,
                                           int row0, int kc,
                                           unsigned short* hi, unsigned short* lo,
                                           int t) {
#pragma unroll
  for (int i = 0; i < 8; ++i) {
    int f   = i * 256 + t;
    int row = f >> 4;
    int q   = f & 15;
    const float4 v = *(const float4*)&src[(size_t)(row0 + row) * 256 + kc + q * 4];
    _Float16 h0 = (_Float16)v.x, h1 = (_Float16)v.y,
             h2 = (_Float16)v.z, h3 = (_Float16)v.w;
    _Float16 l0 = (_Float16)(v.x - (float)h0), l1 = (_Float16)(v.y - (float)h1),
             l2 = (_Float16)(v.z - (float)h2), l3 = (_Float16)(v.w - (float)h3);
    unsigned int off = (unsigned int)(row * 128 + q * 8) ^ ((row & 7) << 4);
    union { _Float16 h[4]; uint2 u; } ph, pl;
    ph.h[0] = h0; ph.h[1] = h1; ph.h[2] = h2; ph.h[3] = h3;
    pl.h[0] = l0; pl.h[1] = l1; pl.h[2] = l2; pl.h[3] = l3;
    *(uint2*)((char*)hi + off) = ph.u;
    *(uint2*)((char*)lo + off) = pl.u;
  }
}

__global__ __launch_bounds__(256, 2) void xp_gemm(
    const float* __restrict__ x,   const float* __restrict__ Wih,
    const float* __restrict__ bih, const float* __restrict__ bhh,
    float* __restrict__ out) {
  __shared__ __align__(16) unsigned short Ah[BM * BK], Al[BM * BK];
  __shared__ __align__(16) unsigned short Bh[BN * BK], Bl[BN * BK];
  const int t    = threadIdx.x;
  const int m0   = blockIdx.x * BM;
  const int n0   = blockIdx.y * BN;
  const int lane = t & 63;
  const int wave = t >> 6;
  const int wm = wave >> 1, wn = wave & 1;

  f32x4 acc[4][4];
#pragma unroll
  for (int i = 0; i < 4; ++i)
#pragma unroll
    for (int j = 0; j < 4; ++j) acc[i][j] = (f32x4)0.0f;

  for (int kc = 0; kc < 256; kc += BK) {
    stage_tile(x,   m0, kc, Ah, Al, t);
    stage_tile(Wih, n0, kc, Bh, Bl, t);
    __syncthreads();
#pragma unroll
    for (int ks = 0; ks < 2; ++ks) {
      f16x8 ah[4], al[4], bh[4], bl[4];
#pragma unroll
      for (int mi = 0; mi < 4; ++mi) {
        int row = wm * 64 + mi * 16 + (lane & 15);
        unsigned int off =
            (unsigned int)(row * 128 + ks * 64 + ((lane >> 4) << 4)) ^ ((row & 7) << 4);
        ah[mi] = *(const f16x8*)((const char*)Ah + off);
        al[mi] = *(const f16x8*)((const char*)Al + off);
      }
#pragma unroll
      for (int ni = 0; ni < 4; ++ni) {
        int row = wn * 64 + ni * 16 + (lane & 15);
        unsigned int off =
            (unsigned int)(row * 128 + ks * 64 + ((lane >> 4) << 4)) ^ ((row & 7) << 4);
        bh[ni] = *(const f16x8*)((const char*)Bh + off);
        bl[ni] = *(const f16x8*)((const char*)Bl + off);
      }
#pragma unroll
      for (int mi = 0; mi < 4; ++mi)
#pragma unroll
        for (int ni = 0; ni < 4; ++ni) {
          acc[mi][ni] = __builtin_amdgcn_mfma_f32_16x16x32_f16(ah[mi], bh[ni], acc[mi][ni], 0, 0, 0);
          acc[mi][ni] = __builtin_amdgcn_mfma_f32_16x16x32_f16(ah[mi], bl[ni], acc[mi][ni], 0, 0, 0);
          acc[mi][ni] = __builtin_amdgcn_mfma_f32_16x16x32_f16(al[mi], bh[ni], acc[mi][ni], 0, 0, 0);
        }
    }
    __syncthreads();
  }
#pragma unroll
  for (int ni = 0; ni < 4; ++ni) {
    int col = n0 + wn * 64 + ni * 16 + (lane & 15);
    float bias = bih[col] + bhh[col];
#pragma unroll
    for (int mi = 0; mi < 4; ++mi) {
      int rbase = m0 + wm * 64 + mi * 16 + ((lane >> 4) << 2);
#pragma unroll
      for (int r = 0; r < 4; ++r)
        out[(size_t)(rbase + r) * DH + col] = acc[mi][ni][r] + bias;
    }
  }
}

// ---------------------------------------------------------------------------
// Kernel 2: DPP-systolic recurrence. 1 WG / batch element, 512 threads
// (8 waves, 2/SIMD). Lane (R=lane>>4, c=lane&15): owns outputs
// j0 = wave*32 + c*2 (+0,+1) over k in [64R, 64R+64). Holds its h-quad
// h[64R+4c..+3] in 4 VGPRs (ONE ds_read_b128/thread/step). The 16-position
// k-rotation is done by v_fmac_f32_dpp row_ror:r -- h broadcast rides the
// FMA operand path (VALU), not the DS pipe. W pre-permuted per lane at load
// (q = (c - r) & 15, matching row_ror reading lane n-r). Row-reduce KS=4 via
// 2 shfl_xor stages. Double-buffered hs => one barrier/step.
// ---------------------------------------------------------------------------
__device__ __forceinline__ float tanh_fast(float x) {
  float xc = fminf(9.0f, fmaxf(-9.0f, x));
  float e2 = __builtin_amdgcn_exp2f(2.885390082f * xc);
  return 1.0f - 2.0f * __builtin_amdgcn_rcpf(e2 + 1.0f);
}

#define FMAC_DPP(acc, hv, wv, RR)                                              \
  asm("v_fmac_f32_dpp %0, %1, %2 row_ror:" #RR " row_mask:0xf bank_mask:0xf"   \
      : "+v"(acc) : "v"(hv), "v"(wv))

// rotation r, 8 fmacs (2 outputs x 4 elems), 4 independent acc chains
#define RMAC(RR)                                                               \
    FMAC_DPP(a0x, hq.x, w0[RR].x, RR); FMAC_DPP(a1x, hq.x, w1[RR].x, RR);      \
    FMAC_DPP(a0z, hq.z, w0[RR].z, RR); FMAC_DPP(a1z, hq.z, w1[RR].z, RR);      \
    FMAC_DPP(a0x, hq.y, w0[RR].y, RR); FMAC_DPP(a1x, hq.y, w1[RR].y, RR);      \
    FMAC_DPP(a0z, hq.w, w0[RR].w, RR); FMAC_DPP(a1z, hq.w, w1[RR].w, RR);

__global__ __launch_bounds__(512, 2) void rnn_rec(
    const float* __restrict__ Whh, float* __restrict__ xh) {
  const int b    = blockIdx.x;
  const int t    = threadIdx.x;
  const int lane = t & 63;
  const int wv   = t >> 6;        // 0..7
  const int R    = lane >> 4;     // 0..3 : k-range [64R, 64R+64)
  const int c    = lane & 15;     // 0..15
  const int j0   = wv * 32 + c * 2;

  __shared__ __align__(16) float hs[2][DH];

  // W pre-permuted into rotation order (q = (c - r) & 15)
  float4 w0[16], w1[16];
#pragma unroll
  for (int r = 0; r < 16; ++r) {
    int q = (c - r) & 15;
    const float* base = Whh + (size_t)j0 * DH + R * 64 + q * 4;
    w0[r] = *(const float4*)base;
    w1[r] = *(const float4*)(base + DH);
  }

  const bool writer = (R == 0);
  float* pcol = xh + (size_t)b * DH + j0;          // + s*32768 per step
  const char* h0b = (const char*)&hs[0][0] + (R * 256 + c * 16);
  const char* h1b = (const char*)&hs[1][0] + (R * 256 + c * 16);

  if (t < DH) hs[0][t] = 0.0f;
  float xpc0 = 0.0f, xpc1 = 0.0f;
  if (writer) { float2 v = *(const float2*)pcol; xpc0 = v.x; xpc1 = v.y; }
  __syncthreads();

#define STEP(S, P)                                                             \
  {                                                                            \
    float4 hq = *(const float4*)((P) ? h1b : h0b);                             \
    float xpn0 = 0.0f, xpn1 = 0.0f;                                            \
    if (writer && (S) + 1 < T_STEPS) {                                         \
      float2 nv = *(const float2*)(pcol + ((size_t)(S) + 1) * (BATCH * DH));   \
      xpn0 = nv.x; xpn1 = nv.y;                                                \
    }                                                                          \
    float a0x = hq.x * w0[0].x, a1x = hq.x * w1[0].x;                          \
    float a0z = hq.z * w0[0].z, a1z = hq.z * w1[0].z;                          \
    a0x = fmaf(hq.y, w0[0].y, a0x); a1x = fmaf(hq.y, w1[0].y, a1x);            \
    a0z = fmaf(hq.w, w0[0].w, a0z); a1z = fmaf(hq.w, w1[0].w, a1z);            \
    RMAC(1)  RMAC(2)  RMAC(3)  RMAC(4)  RMAC(5)  RMAC(6)  RMAC(7)  RMAC(8)    \
    RMAC(9)  RMAC(10) RMAC(11) RMAC(12) RMAC(13) RMAC(14) RMAC(15)            \
    float a0 = a0x + a0z, a1 = a1x + a1z;                                      \
    a0 += __shfl_xor(a0, 32, 64); a1 += __shfl_xor(a1, 32, 64);                \
    a0 += __shfl_xor(a0, 16, 64); a1 += __shfl_xor(a1, 16, 64);                \
    if (writer) {                                                              \
      float hn0 = tanh_fast(a0 + xpc0);                                        \
      float hn1 = tanh_fast(a1 + xpc1);                                        \
      *(float2*)&hs[(P) ^ 1][j0] = make_float2(hn0, hn1);                      \
      *(float2*)(pcol + (size_t)(S) * (BATCH * DH)) = make_float2(hn0, hn1);   \
    }                                                                          \
    xpc0 = xpn0; xpc1 = xpn1;                                                  \
    __syncthreads();                                                           \
  }

  for (int s = 0; s < T_STEPS; s += 2) {
    STEP(s, 0)
    STEP(s + 1, 1)
  }
#undef STEP
}

extern "C" void kernel_launch(void* const* d_in, const int* in_sizes, int n_in,
                              void* d_out, int out_size, void* d_ws, size_t ws_size,
                              hipStream_t stream) {
  const float* x   = (const float*)d_in[0];
  const float* Wih = (const float*)d_in[1];
  const float* Whh = (const float*)d_in[2];
  const float* bih = (const float*)d_in[3];
  const float* bhh = (const float*)d_in[4];
  float* out = (float*)d_out;

  dim3 g1((T_STEPS * BATCH) / BM, DH / BN);   // 1024 x 2
  xp_gemm<<<g1, dim3(256), 0, stream>>>(x, Wih, bih, bhh, out);
  rnn_rec<<<BATCH, dim3(512), 0, stream>>>(Whh, out);
}

// Round 4
// 793.244 us; speedup vs baseline: 1.1847x; 1.1847x over previous
//
#include <hip/hip_runtime.h>
#include <hip/hip_bf16.h>

typedef _Float16 f16x8 __attribute__((ext_vector_type(8)));
typedef float    f32x4 __attribute__((ext_vector_type(4)));

#define T_STEPS 1024
#define BATCH   128
#define DH      256

// ---------------------------------------------------------------------------
// Kernel 1 (unchanged, 87us): xp = x @ W_ih^T + b_ih + b_hh -> d_out.
// f16 hi/lo split (3 MFMA passes) => ~fp32 accuracy.
// ---------------------------------------------------------------------------
#define BM 128
#define BN 128
#define BK 64

__device__ __forceinline__ void stage_tile(const float* __restrict__ src,
                                           int row0, int kc,
                                           unsigned short* hi, unsigned short* lo,
                                           int t) {
#pragma unroll
  for (int i = 0; i < 8; ++i) {
    int f   = i * 256 + t;
    int row = f >> 4;
    int q   = f & 15;
    const float4 v = *(const float4*)&src[(size_t)(row0 + row) * 256 + kc + q * 4];
    _Float16 h0 = (_Float16)v.x, h1 = (_Float16)v.y,
             h2 = (_Float16)v.z, h3 = (_Float16)v.w;
    _Float16 l0 = (_Float16)(v.x - (float)h0), l1 = (_Float16)(v.y - (float)h1),
             l2 = (_Float16)(v.z - (float)h2), l3 = (_Float16)(v.w - (float)h3);
    unsigned int off = (unsigned int)(row * 128 + q * 8) ^ ((row & 7) << 4);
    union { _Float16 h[4]; uint2 u; } ph, pl;
    ph.h[0] = h0; ph.h[1] = h1; ph.h[2] = h2; ph.h[3] = h3;
    pl.h[0] = l0; pl.h[1] = l1; pl.h[2] = l2; pl.h[3] = l3;
    *(uint2*)((char*)hi + off) = ph.u;
    *(uint2*)((char*)lo + off) = pl.u;
  }
}

__global__ __launch_bounds__(256, 2) void xp_gemm(
    const float* __restrict__ x,   const float* __restrict__ Wih,
    const float* __restrict__ bih, const float* __restrict__ bhh,
    float* __restrict__ out) {
  __shared__ __align__(16) unsigned short Ah[BM * BK], Al[BM * BK];
  __shared__ __align__(16) unsigned short Bh[BN * BK], Bl[BN * BK];
  const int t    = threadIdx.x;
  const int m0   = blockIdx.x * BM;
  const int n0   = blockIdx.y * BN;
  const int lane = t & 63;
  const int wave = t >> 6;
  const int wm = wave >> 1, wn = wave & 1;

  f32x4 acc[4][4];
#pragma unroll
  for (int i = 0; i < 4; ++i)
#pragma unroll
    for (int j = 0; j < 4; ++j) acc[i][j] = (f32x4)0.0f;

  for (int kc = 0; kc < 256; kc += BK) {
    stage_tile(x,   m0, kc, Ah, Al, t);
    stage_tile(Wih, n0, kc, Bh, Bl, t);
    __syncthreads();
#pragma unroll
    for (int ks = 0; ks < 2; ++ks) {
      f16x8 ah[4], al[4], bh[4], bl[4];
#pragma unroll
      for (int mi = 0; mi < 4; ++mi) {
        int row = wm * 64 + mi * 16 + (lane & 15);
        unsigned int off =
            (unsigned int)(row * 128 + ks * 64 + ((lane >> 4) << 4)) ^ ((row & 7) << 4);
        ah[mi] = *(const f16x8*)((const char*)Ah + off);
        al[mi] = *(const f16x8*)((const char*)Al + off);
      }
#pragma unroll
      for (int ni = 0; ni < 4; ++ni) {
        int row = wn * 64 + ni * 16 + (lane & 15);
        unsigned int off =
            (unsigned int)(row * 128 + ks * 64 + ((lane >> 4) << 4)) ^ ((row & 7) << 4);
        bh[ni] = *(const f16x8*)((const char*)Bh + off);
        bl[ni] = *(const f16x8*)((const char*)Bl + off);
      }
#pragma unroll
      for (int mi = 0; mi < 4; ++mi)
#pragma unroll
        for (int ni = 0; ni < 4; ++ni) {
          acc[mi][ni] = __builtin_amdgcn_mfma_f32_16x16x32_f16(ah[mi], bh[ni], acc[mi][ni], 0, 0, 0);
          acc[mi][ni] = __builtin_amdgcn_mfma_f32_16x16x32_f16(ah[mi], bl[ni], acc[mi][ni], 0, 0, 0);
          acc[mi][ni] = __builtin_amdgcn_mfma_f32_16x16x32_f16(al[mi], bh[ni], acc[mi][ni], 0, 0, 0);
        }
    }
    __syncthreads();
  }
#pragma unroll
  for (int ni = 0; ni < 4; ++ni) {
    int col = n0 + wn * 64 + ni * 16 + (lane & 15);
    float bias = bih[col] + bhh[col];
#pragma unroll
    for (int mi = 0; mi < 4; ++mi) {
      int rbase = m0 + wm * 64 + mi * 16 + ((lane >> 4) << 2);
#pragma unroll
      for (int r = 0; r < 4; ++r)
        out[(size_t)(rbase + r) * DH + col] = acc[mi][ni][r] + bias;
    }
  }
}

// ---------------------------------------------------------------------------
// Kernel 2: recurrence, DS-minimal. 1 WG/batch, 512 threads (8 waves, 2/SIMD).
// Thread (wave wv, row r=lane>>4, col c=lane&15): owns 8 outputs
// jb=wv*32+r*8 over k-slice [16c,16c+16). W = 128 floats in plain-C unrolled
// arrays (compiler-managed VGPRs; no asm pinning -- R3 lesson). Per step:
//   * 4x ds_read_b128 of h (q-rotated by c => 2-way banks, free)  [DS: 32/CU]
//   * 128 FMA into 8 acc chains                                    [VALU]
//   * 4-stage v_add_f32_dpp row_ror butterfly over the 16 c-lanes  [VALU!]
//     (reduction OFF the DS pipe -- R1/R2 lesson)
//   * cndmask-select a[c&7], tanh_fast, lanes c<8 write h
// Double-buffered hs + phase unroll => ONE barrier/step.
// ---------------------------------------------------------------------------
__device__ __forceinline__ float tanh_fast(float x) {
  float xc = fminf(9.0f, fmaxf(-9.0f, x));
  float e2 = __builtin_amdgcn_exp2f(2.885390082f * xc);
  return 1.0f - 2.0f * __builtin_amdgcn_rcpf(e2 + 1.0f);
}

// sum over the 16 lanes of a DPP row via rotate-butterfly (all lanes get sum)
__device__ __forceinline__ float dpp_ror_sum16(float x) {
  float y;
  asm("v_add_f32_dpp %0, %1, %1 row_ror:8 row_mask:0xf bank_mask:0xf"
      : "=v"(y) : "v"(x));
  asm("v_add_f32_dpp %0, %1, %1 row_ror:4 row_mask:0xf bank_mask:0xf"
      : "=v"(x) : "v"(y));
  asm("v_add_f32_dpp %0, %1, %1 row_ror:2 row_mask:0xf bank_mask:0xf"
      : "=v"(y) : "v"(x));
  asm("v_add_f32_dpp %0, %1, %1 row_ror:1 row_mask:0xf bank_mask:0xf"
      : "=v"(x) : "v"(y));
  return x;
}

__global__ __launch_bounds__(512) void rnn_rec(
    const float* __restrict__ Whh, float* __restrict__ xh) {
  const int b    = blockIdx.x;
  const int t    = threadIdx.x;
  const int lane = t & 63;
  const int wv   = t >> 6;        // 0..7
  const int r    = lane >> 4;     // 0..3
  const int c    = lane & 15;     // 0..15  (k-group)
  const int jb   = wv * 32 + r * 8;

  __shared__ __align__(16) float hs[2][DH];

  // W[j'][q*4+e] = Whh[jb+j'][16c + 4*((q+c)&3) + e]  (rotation matches h read)
  float w[8][16];
#pragma unroll
  for (int j = 0; j < 8; ++j)
#pragma unroll
    for (int q = 0; q < 4; ++q)
      *(float4*)&w[j][q * 4] =
          *(const float4*)&Whh[(size_t)(jb + j) * DH + 16 * c + 4 * ((q + c) & 3)];

  unsigned hoff[4];
#pragma unroll
  for (int q = 0; q < 4; ++q) hoff[q] = 64u * c + 16u * ((q + c) & 3);

  const bool writer = (c < 8);
  const int  j      = jb + (c & 7);
  float* pcol = xh + (size_t)b * DH + j;
  const char* hb0 = (const char*)&hs[0][0];
  const char* hb1 = (const char*)&hs[1][0];

  if (t < DH) hs[0][t] = 0.0f;
  float xpc = 0.0f;
  if (writer) xpc = pcol[0];
  __syncthreads();

#define STEP(S, P)                                                             \
  {                                                                            \
    float xpn = 0.0f;                                                          \
    if (writer && (S) + 1 < T_STEPS)                                           \
      xpn = pcol[((size_t)(S) + 1) * (BATCH * DH)];                            \
    const char* hb = (P) ? hb1 : hb0;                                          \
    float4 hq0 = *(const float4*)(hb + hoff[0]);                               \
    float4 hq1 = *(const float4*)(hb + hoff[1]);                               \
    float4 hq2 = *(const float4*)(hb + hoff[2]);                               \
    float4 hq3 = *(const float4*)(hb + hoff[3]);                               \
    float hv[16] = {hq0.x, hq0.y, hq0.z, hq0.w, hq1.x, hq1.y, hq1.z, hq1.w,    \
                    hq2.x, hq2.y, hq2.z, hq2.w, hq3.x, hq3.y, hq3.z, hq3.w};   \
    float a[8];                                                                \
    _Pragma("unroll")                                                          \
    for (int jj = 0; jj < 8; ++jj) a[jj] = w[jj][0] * hv[0];                   \
    _Pragma("unroll")                                                          \
    for (int kk = 1; kk < 16; ++kk)                                            \
      _Pragma("unroll")                                                        \
      for (int jj = 0; jj < 8; ++jj)                                           \
        a[jj] = fmaf(w[jj][kk], hv[kk], a[jj]);                                \
    _Pragma("unroll")                                                          \
    for (int jj = 0; jj < 8; ++jj) a[jj] = dpp_ror_sum16(a[jj]);               \
    const int cc = c & 7;                                                      \
    float v0 = (cc & 1) ? a[1] : a[0];                                         \
    float v1 = (cc & 1) ? a[3] : a[2];                                         \
    float v2 = (cc & 1) ? a[5] : a[4];                                         \
    float v3 = (cc & 1) ? a[7] : a[6];                                         \
    float u0 = (cc & 2) ? v1 : v0;                                             \
    float u1 = (cc & 2) ? v3 : v2;                                             \
    float sum = (cc & 4) ? u1 : u0;                                            \
    float h = tanh_fast(sum + xpc);                                            \
    if (writer) {                                                              \
      hs[(P) ^ 1][j] = h;                                                      \
      pcol[(size_t)(S) * (BATCH * DH)] = h;                                    \
    }                                                                          \
    xpc = xpn;                                                                 \
    __syncthreads();                                                           \
  }

  for (int s = 0; s < T_STEPS; s += 2) {
    STEP(s, 0)
    STEP(s + 1, 1)
  }
#undef STEP
}

extern "C" void kernel_launch(void* const* d_in, const int* in_sizes, int n_in,
                              void* d_out, int out_size, void* d_ws, size_t ws_size,
                              hipStream_t stream) {
  const float* x   = (const float*)d_in[0];
  const float* Wih = (const float*)d_in[1];
  const float* Whh = (const float*)d_in[2];
  const float* bih = (const float*)d_in[3];
  const float* bhh = (const float*)d_in[4];
  float* out = (float*)d_out;

  dim3 g1((T_STEPS * BATCH) / BM, DH / BN);   // 1024 x 2
  xp_gemm<<<g1, dim3(256), 0, stream>>>(x, Wih, bih, bhh, out);
  rnn_rec<<<BATCH, dim3(512), 0, stream>>>(Whh, out);
}

// Round 5
// 725.660 us; speedup vs baseline: 1.2950x; 1.0931x over previous
//
#include <hip/hip_runtime.h>
#include <hip/hip_bf16.h>

typedef _Float16 f16x8 __attribute__((ext_vector_type(8)));
typedef float    f32x4 __attribute__((ext_vector_type(4)));
typedef float    f32x2 __attribute__((ext_vector_type(2)));

#define T_STEPS 1024
#define BATCH   128
#define DH      256

// ---------------------------------------------------------------------------
// Kernel 1 (unchanged, ~87us): xp = x @ W_ih^T + b_ih + b_hh -> d_out.
// f16 hi/lo split (3 MFMA passes) => ~fp32 accuracy.
// ---------------------------------------------------------------------------
#define BM 128
#define BN 128
#define BK 64

__device__ __forceinline__ void stage_tile(const float* __restrict__ src,
                                           int row0, int kc,
                                           unsigned short* hi, unsigned short* lo,
                                           int t) {
#pragma unroll
  for (int i = 0; i < 8; ++i) {
    int f   = i * 256 + t;
    int row = f >> 4;
    int q   = f & 15;
    const float4 v = *(const float4*)&src[(size_t)(row0 + row) * 256 + kc + q * 4];
    _Float16 h0 = (_Float16)v.x, h1 = (_Float16)v.y,
             h2 = (_Float16)v.z, h3 = (_Float16)v.w;
    _Float16 l0 = (_Float16)(v.x - (float)h0), l1 = (_Float16)(v.y - (float)h1),
             l2 = (_Float16)(v.z - (float)h2), l3 = (_Float16)(v.w - (float)h3);
    unsigned int off = (unsigned int)(row * 128 + q * 8) ^ ((row & 7) << 4);
    union { _Float16 h[4]; uint2 u; } ph, pl;
    ph.h[0] = h0; ph.h[1] = h1; ph.h[2] = h2; ph.h[3] = h3;
    pl.h[0] = l0; pl.h[1] = l1; pl.h[2] = l2; pl.h[3] = l3;
    *(uint2*)((char*)hi + off) = ph.u;
    *(uint2*)((char*)lo + off) = pl.u;
  }
}

__global__ __launch_bounds__(256, 2) void xp_gemm(
    const float* __restrict__ x,   const float* __restrict__ Wih,
    const float* __restrict__ bih, const float* __restrict__ bhh,
    float* __restrict__ out) {
  __shared__ __align__(16) unsigned short Ah[BM * BK], Al[BM * BK];
  __shared__ __align__(16) unsigned short Bh[BN * BK], Bl[BN * BK];
  const int t    = threadIdx.x;
  const int m0   = blockIdx.x * BM;
  const int n0   = blockIdx.y * BN;
  const int lane = t & 63;
  const int wave = t >> 6;
  const int wm = wave >> 1, wn = wave & 1;

  f32x4 acc[4][4];
#pragma unroll
  for (int i = 0; i < 4; ++i)
#pragma unroll
    for (int j = 0; j < 4; ++j) acc[i][j] = (f32x4)0.0f;

  for (int kc = 0; kc < 256; kc += BK) {
    stage_tile(x,   m0, kc, Ah, Al, t);
    stage_tile(Wih, n0, kc, Bh, Bl, t);
    __syncthreads();
#pragma unroll
    for (int ks = 0; ks < 2; ++ks) {
      f16x8 ah[4], al[4], bh[4], bl[4];
#pragma unroll
      for (int mi = 0; mi < 4; ++mi) {
        int row = wm * 64 + mi * 16 + (lane & 15);
        unsigned int off =
            (unsigned int)(row * 128 + ks * 64 + ((lane >> 4) << 4)) ^ ((row & 7) << 4);
        ah[mi] = *(const f16x8*)((const char*)Ah + off);
        al[mi] = *(const f16x8*)((const char*)Al + off);
      }
#pragma unroll
      for (int ni = 0; ni < 4; ++ni) {
        int row = wn * 64 + ni * 16 + (lane & 15);
        unsigned int off =
            (unsigned int)(row * 128 + ks * 64 + ((lane >> 4) << 4)) ^ ((row & 7) << 4);
        bh[ni] = *(const f16x8*)((const char*)Bh + off);
        bl[ni] = *(const f16x8*)((const char*)Bl + off);
      }
#pragma unroll
      for (int mi = 0; mi < 4; ++mi)
#pragma unroll
        for (int ni = 0; ni < 4; ++ni) {
          acc[mi][ni] = __builtin_amdgcn_mfma_f32_16x16x32_f16(ah[mi], bh[ni], acc[mi][ni], 0, 0, 0);
          acc[mi][ni] = __builtin_amdgcn_mfma_f32_16x16x32_f16(ah[mi], bl[ni], acc[mi][ni], 0, 0, 0);
          acc[mi][ni] = __builtin_amdgcn_mfma_f32_16x16x32_f16(al[mi], bh[ni], acc[mi][ni], 0, 0, 0);
        }
    }
    __syncthreads();
  }
#pragma unroll
  for (int ni = 0; ni < 4; ++ni) {
    int col = n0 + wn * 64 + ni * 16 + (lane & 15);
    float bias = bih[col] + bhh[col];
#pragma unroll
    for (int mi = 0; mi < 4; ++mi) {
      int rbase = m0 + wm * 64 + mi * 16 + ((lane >> 4) << 2);
#pragma unroll
      for (int r = 0; r < 4; ++r)
        out[(size_t)(rbase + r) * DH + col] = acc[mi][ni][r] + bias;
    }
  }
}

// ---------------------------------------------------------------------------
// Kernel 2: recurrence. 1 WG/batch, 512 threads (8 waves, pinned 2/EU so the
// allocator gets the full 256-VGPR budget -- kills the AGPR spill seen R1-R4).
// Thread (wave wv, r=lane>>4, c=lane&15): owns 8 outputs jb=wv*32+r*8 over
// k-slice {64q+4c+e : q=0..3, e=0..3}. Per step:
//   * 4x ds_read_b128 of h at byte 16c + {0,256,512,768}: 16 lanes read 256
//     contiguous bytes => perfect 2-way bank tiling (free), r-copies broadcast.
//   * 64x v_pk_fma_f32 (k-pairs in lo/hi, default op_sel) -> 8 f32x2 accs.
//   * 8 k-parity merge adds; 4-stage v_add_f32_dpp row_ror butterfly (VALU).
//   * cndmask select, tanh_fast, lanes c<8 write h to LDS + global.
// Double-buffered hs + phase unroll => ONE barrier/step.
// ---------------------------------------------------------------------------
__device__ __forceinline__ float tanh_fast(float x) {
  float xc = fminf(9.0f, fmaxf(-9.0f, x));
  float e2 = __builtin_amdgcn_exp2f(2.885390082f * xc);
  return 1.0f - 2.0f * __builtin_amdgcn_rcpf(e2 + 1.0f);
}

__device__ __forceinline__ float dpp_ror_sum16(float x) {
  float y;
  asm("v_add_f32_dpp %0, %1, %1 row_ror:8 row_mask:0xf bank_mask:0xf"
      : "=v"(y) : "v"(x));
  asm("v_add_f32_dpp %0, %1, %1 row_ror:4 row_mask:0xf bank_mask:0xf"
      : "=v"(x) : "v"(y));
  asm("v_add_f32_dpp %0, %1, %1 row_ror:2 row_mask:0xf bank_mask:0xf"
      : "=v"(y) : "v"(x));
  asm("v_add_f32_dpp %0, %1, %1 row_ror:1 row_mask:0xf bank_mask:0xf"
      : "=v"(x) : "v"(y));
  return x;
}

#define PKMUL(a, w, h) \
  asm("v_pk_mul_f32 %0, %1, %2"     : "=v"(a) : "v"(w), "v"(h))
#define PKFMA(a, w, h) \
  asm("v_pk_fma_f32 %0, %1, %2, %0" : "+v"(a) : "v"(w), "v"(h))

__attribute__((amdgpu_waves_per_eu(2, 2)))
__global__ __launch_bounds__(512) void rnn_rec(
    const float* __restrict__ Whh, float* __restrict__ xh) {
  const int b    = blockIdx.x;
  const int t    = threadIdx.x;
  const int lane = t & 63;
  const int wv   = t >> 6;        // 0..7
  const int r    = lane >> 4;     // 0..3
  const int c    = lane & 15;     // 0..15
  const int jb   = wv * 32 + r * 8;

  __shared__ __align__(16) float hs[2][DH];

  // W rows jb..jb+7, k-slice {64q+4c..+3} -> 64 f32x2 (k-pairs), coalesced f4 loads
  f32x2 w2[8][8];
#pragma unroll
  for (int j = 0; j < 8; ++j)
#pragma unroll
    for (int q = 0; q < 4; ++q) {
      float4 v = *(const float4*)&Whh[(size_t)(jb + j) * DH + 64 * q + 4 * c];
      f32x2 lo; lo[0] = v.x; lo[1] = v.y;
      f32x2 hi; hi[0] = v.z; hi[1] = v.w;
      w2[j][2 * q]     = lo;
      w2[j][2 * q + 1] = hi;
    }

  const bool writer = (c < 8);
  const int  j      = jb + (c & 7);
  float* pcol = xh + (size_t)b * DH + j;
  const char* hb0 = (const char*)&hs[0][0] + 16 * c;
  const char* hb1 = (const char*)&hs[1][0] + 16 * c;

  if (t < DH) hs[0][t] = 0.0f;
  float xpc = 0.0f;
  if (writer) xpc = pcol[0];
  __syncthreads();

#define STEP(S, P)                                                             \
  {                                                                            \
    float xpn = 0.0f;                                                          \
    if (writer && (S) + 1 < T_STEPS)                                           \
      xpn = pcol[((size_t)(S) + 1) * (BATCH * DH)];                            \
    const char* hb = (P) ? hb1 : hb0;                                          \
    float4 hq0 = *(const float4*)(hb);                                         \
    float4 hq1 = *(const float4*)(hb + 256);                                   \
    float4 hq2 = *(const float4*)(hb + 512);                                   \
    float4 hq3 = *(const float4*)(hb + 768);                                   \
    f32x2 hp[8];                                                               \
    hp[0][0] = hq0.x; hp[0][1] = hq0.y;  hp[1][0] = hq0.z; hp[1][1] = hq0.w;   \
    hp[2][0] = hq1.x; hp[2][1] = hq1.y;  hp[3][0] = hq1.z; hp[3][1] = hq1.w;   \
    hp[4][0] = hq2.x; hp[4][1] = hq2.y;  hp[5][0] = hq2.z; hp[5][1] = hq2.w;   \
    hp[6][0] = hq3.x; hp[6][1] = hq3.y;  hp[7][0] = hq3.z; hp[7][1] = hq3.w;   \
    f32x2 acc[8];                                                              \
    _Pragma("unroll")                                                          \
    for (int jj = 0; jj < 8; ++jj) PKMUL(acc[jj], w2[jj][0], hp[0]);           \
    _Pragma("unroll")                                                          \
    for (int kp = 1; kp < 8; ++kp)                                             \
      _Pragma("unroll")                                                        \
      for (int jj = 0; jj < 8; ++jj) PKFMA(acc[jj], w2[jj][kp], hp[kp]);       \
    float a[8];                                                                \
    _Pragma("unroll")                                                          \
    for (int jj = 0; jj < 8; ++jj) a[jj] = acc[jj][0] + acc[jj][1];            \
    _Pragma("unroll")                                                          \
    for (int jj = 0; jj < 8; ++jj) a[jj] = dpp_ror_sum16(a[jj]);               \
    const int cc = c & 7;                                                      \
    float v0 = (cc & 1) ? a[1] : a[0];                                         \
    float v1 = (cc & 1) ? a[3] : a[2];                                         \
    float v2 = (cc & 1) ? a[5] : a[4];                                         \
    float v3 = (cc & 1) ? a[7] : a[6];                                         \
    float u0 = (cc & 2) ? v1 : v0;                                             \
    float u1 = (cc & 2) ? v3 : v2;                                             \
    float sum = (cc & 4) ? u1 : u0;                                            \
    float h = tanh_fast(sum + xpc);                                            \
    if (writer) {                                                              \
      hs[(P) ^ 1][j] = h;                                                      \
      pcol[(size_t)(S) * (BATCH * DH)] = h;                                    \
    }                                                                          \
    xpc = xpn;                                                                 \
    __syncthreads();                                                           \
  }

  for (int s = 0; s < T_STEPS; s += 2) {
    STEP(s, 0)
    STEP(s + 1, 1)
  }
#undef STEP
}

extern "C" void kernel_launch(void* const* d_in, const int* in_sizes, int n_in,
                              void* d_out, int out_size, void* d_ws, size_t ws_size,
                              hipStream_t stream) {
  const float* x   = (const float*)d_in[0];
  const float* Wih = (const float*)d_in[1];
  const float* Whh = (const float*)d_in[2];
  const float* bih = (const float*)d_in[3];
  const float* bhh = (const float*)d_in[4];
  float* out = (float*)d_out;

  dim3 g1((T_STEPS * BATCH) / BM, DH / BN);   // 1024 x 2
  xp_gemm<<<g1, dim3(256), 0, stream>>>(x, Wih, bih, bhh, out);
  rnn_rec<<<BATCH, dim3(512), 0, stream>>>(Whh, out);
}